// Round 23
// baseline (151.962 us; speedup 1.0000x reference)
//
#include <hip/hip_runtime.h>

#define N_NODES 50000
#define E_EDGES 800000
#define FEAT    128
#define KORD    3
#define BN_EPS  1e-5f
#define NBUK    49          // coarse buckets (dst >> 10)
#define BCAP    20480       // bucket capacity
#define NSHARD  16          // BN-stats atomic shards
#define NSEG    128         // bucketB segments per bucket (~1 edge/thread)
#define NGC_BLKS 3125       // g_cast main blocks: 16 nodes/block
#define NWB_BLKS 12500      // segagg blocks (1 node/wave)
#define NZERO   4352        // ints to zero: sbuf(4096) + gcur(256)

typedef __fp16 f16x2 __attribute__((ext_vector_type(2)));
typedef __fp16 f16x8 __attribute__((ext_vector_type(8)));
typedef __attribute__((ext_vector_type(4))) float f32x4;

__device__ __forceinline__ unsigned h2u(f16x2 h) { union { f16x2 h; unsigned u; } c; c.h = h; return c.u; }
__device__ __forceinline__ f16x2 u2h(unsigned u) { union { unsigned u; f16x2 h; } c; c.u = u; return c.h; }

// async global->LDS, 16B per lane (lane lands at ldsbase + lane*16)
__device__ __forceinline__ void gload16(const void* g, void* l) {
    __builtin_amdgcn_global_load_lds(
        (const __attribute__((address_space(1))) unsigned int*)g,
        (__attribute__((address_space(3))) unsigned int*)l, 16, 0, 0);
}

// ---- per node: feature->f16, pack {coords, g=attW@f}; zero sbuf/gcur;
//      tail blocks: fold GT[o][k*128+i] = sum_j L[k][i][j]*W[o][j] ----
__global__ void g_cast(const float* __restrict__ feat,
                       const float* __restrict__ coords,
                       const float* __restrict__ attW,
                       const float* __restrict__ W,
                       const float* __restrict__ L,
                       __fp16* __restrict__ fh,
                       float4* __restrict__ pk,
                       __fp16* __restrict__ GT,
                       int* __restrict__ zbase) {
    __shared__ float wrow[FEAT];
    const int gtid = blockIdx.x * 256 + threadIdx.x;
    if (gtid < NZERO) zbase[gtid] = 0;       // sbuf + gcur zeroing
    if (blockIdx.x >= NGC_BLKS) {            // gprep tail blocks (128)
        const int o = blockIdx.x - NGC_BLKS;
        const int i = threadIdx.x;
        if (i < FEAT) wrow[i] = W[o * FEAT + i];
        __syncthreads();
        if (i < FEAT) {
            #pragma unroll
            for (int k = 0; k < KORD; ++k) {
                const float* lp = L + ((size_t)k * FEAT + i) * FEAT;
                float acc = 0.f;
                #pragma unroll 8
                for (int j = 0; j < FEAT; ++j) acc = fmaf(lp[j], wrow[j], acc);
                GT[(size_t)o * 384 + k * FEAT + i] = (__fp16)acc;
            }
        }
        return;
    }
    const int node = blockIdx.x * 16 + (threadIdx.x >> 4);
    const int sub  = threadIdx.x & 15;       // 8-feature slice
    const float4 fa = *(const float4*)(feat + (size_t)node * FEAT + sub * 8);
    const float4 fb = *(const float4*)(feat + (size_t)node * FEAT + sub * 8 + 4);
    uint4 ov;
    ov.x = h2u(__builtin_amdgcn_cvt_pkrtz(fa.x, fa.y));
    ov.y = h2u(__builtin_amdgcn_cvt_pkrtz(fa.z, fa.w));
    ov.z = h2u(__builtin_amdgcn_cvt_pkrtz(fb.x, fb.y));
    ov.w = h2u(__builtin_amdgcn_cvt_pkrtz(fb.z, fb.w));
    *(uint4*)(fh + (size_t)node * FEAT + sub * 8) = ov;
    float g0, g1, g2;
    {
        const float4 wa0 = *(const float4*)(attW + 0 * FEAT + sub * 8);
        const float4 wb0 = *(const float4*)(attW + 0 * FEAT + sub * 8 + 4);
        const float4 wa1 = *(const float4*)(attW + 1 * FEAT + sub * 8);
        const float4 wb1 = *(const float4*)(attW + 1 * FEAT + sub * 8 + 4);
        const float4 wa2 = *(const float4*)(attW + 2 * FEAT + sub * 8);
        const float4 wb2 = *(const float4*)(attW + 2 * FEAT + sub * 8 + 4);
        g0 = fa.x*wa0.x + fa.y*wa0.y + fa.z*wa0.z + fa.w*wa0.w
           + fb.x*wb0.x + fb.y*wb0.y + fb.z*wb0.z + fb.w*wb0.w;
        g1 = fa.x*wa1.x + fa.y*wa1.y + fa.z*wa1.z + fa.w*wa1.w
           + fb.x*wb1.x + fb.y*wb1.y + fb.z*wb1.z + fb.w*wb1.w;
        g2 = fa.x*wa2.x + fa.y*wa2.y + fa.z*wa2.z + fa.w*wa2.w
           + fb.x*wb2.x + fb.y*wb2.y + fb.z*wb2.z + fb.w*wb2.w;
    }
    #pragma unroll
    for (int off = 8; off; off >>= 1) {
        g0 += __shfl_xor(g0, off);
        g1 += __shfl_xor(g1, off);
        g2 += __shfl_xor(g2, off);
    }
    if (sub == 0) {
        const float c0 = coords[node * 3 + 0], c1 = coords[node * 3 + 1], c2 = coords[node * 3 + 2];
        pk[2 * node]     = make_float4(c0, c1, c2, g0);
        pk[2 * node + 1] = make_float4(g1, g2, 0.f, 0.f);
    }
}

// ============ CSR build ============
__global__ __launch_bounds__(256)
void bucketA(const int* __restrict__ src, const int* __restrict__ dst,
             const int* __restrict__ order,
             int* __restrict__ gcur, int2* __restrict__ bbuf) {
    __shared__ int lcnt[4][NBUK];
    __shared__ int wbase[4][NBUK];
    const int tid = threadIdx.x;
    const int wid = tid >> 6;
    if (tid < NBUK) {
        lcnt[0][tid] = 0; lcnt[1][tid] = 0; lcnt[2][tid] = 0; lcnt[3][tid] = 0;
    }
    __syncthreads();
    const int e0 = blockIdx.x * 2048;
    int b[8], r[8], so[8], dd[8];
    #pragma unroll
    for (int i = 0; i < 8; ++i) {
        const int e = e0 + i * 256 + tid;
        if (e < E_EDGES) {
            dd[i] = dst[e];
            so[i] = (order[e] << 16) | src[e];
            b[i] = dd[i] >> 10;
            r[i] = atomicAdd(&lcnt[wid][b[i]], 1);
        } else b[i] = -1;
    }
    __syncthreads();
    if (tid < NBUK) {
        const int w0 = lcnt[0][tid], w1 = lcnt[1][tid], w2 = lcnt[2][tid], w3 = lcnt[3][tid];
        const int base = atomicAdd(gcur + tid, w0 + w1 + w2 + w3);
        wbase[0][tid] = base;
        wbase[1][tid] = base + w0;
        wbase[2][tid] = base + w0 + w1;
        wbase[3][tid] = base + w0 + w1 + w2;
    }
    __syncthreads();
    #pragma unroll
    for (int i = 0; i < 8; ++i)
        if (b[i] >= 0)
            bbuf[(size_t)b[i] * BCAP + wbase[wid][b[i]] + r[i]] = make_int2(so[i], dd[i]);
}

// ---- hist2: per-bucket LDS histogram + local scan + cross-bucket prefix ----
__global__ __launch_bounds__(256)
void hist2(const int* __restrict__ gcur, const int2* __restrict__ bbuf,
           int* __restrict__ rowptr, int* __restrict__ cursor) {
    __shared__ int lhist[1024];
    __shared__ int lscan[256];
    __shared__ int boff_s;
    const int b = blockIdx.x;
    const int t = threadIdx.x;
    #pragma unroll
    for (int i = 0; i < 4; ++i) lhist[t + i * 256] = 0;
    __syncthreads();
    const int n = gcur[b];
    const int base = b << 10;
    for (int i = t; i < n; i += 256)
        atomicAdd(&lhist[bbuf[(size_t)b * BCAP + i].y - base], 1);
    __syncthreads();
    if (t < 64) {
        const int v = (t < NBUK) ? gcur[t] : 0;
        int incl = v;
        #pragma unroll
        for (int off = 1; off < 64; off <<= 1) {
            const int u = __shfl_up(incl, off);
            if (t >= off) incl += u;
        }
        if (t == b) boff_s = incl - v;
    }
    int v[4];
    #pragma unroll
    for (int i = 0; i < 4; ++i) v[i] = lhist[t * 4 + i];
    lscan[t] = v[0] + v[1] + v[2] + v[3];
    __syncthreads();
    for (int off = 1; off < 256; off <<= 1) {
        const int u = (t >= off) ? lscan[t - off] : 0;
        __syncthreads();
        lscan[t] += u;
        __syncthreads();
    }
    int excl = (t ? lscan[t - 1] : 0) + boff_s;
    #pragma unroll
    for (int i = 0; i < 4; ++i) {
        const int node = base + t * 4 + i;
        if (node < N_NODES) { rowptr[node] = excl; cursor[node] = excl; }
        excl += v[i];
    }
    if (b == 0 && t == 0) rowptr[N_NODES] = E_EDGES;
}

// ---- bucketB: CSR scatter + per-edge att/invd packed to 8B ----
__global__ void bucketB(const int* __restrict__ gcur, const int2* __restrict__ bbuf,
                        const float4* __restrict__ pk,
                        int* __restrict__ cursor, int2* __restrict__ edata) {
    const int b = blockIdx.x / NSEG;
    const int seg = blockIdx.x % NSEG;
    const int n = gcur[b];
    const int lo = (int)((long)n * seg / NSEG), hi = (int)((long)n * (seg + 1) / NSEG);
    for (int i = lo + (int)threadIdx.x; i < hi; i += 256) {
        const int2 ent = bbuf[(size_t)b * BCAP + i];
        const int s = ent.x & 0xFFFF;
        const int d = ent.y;
        const float4 a0 = pk[2 * s], a1 = pk[2 * s + 1], c0 = pk[2 * d];
        const float dx = a0.x - c0.x, dy = a0.y - c0.y, dz = a0.z - c0.z;
        const float att  = dx * a0.w + dy * a1.x + dz * a1.y;
        const float invd = 1.f / (dx * dx + dy * dy + dz * dz + 1.f);
        const int pos = atomicAdd(cursor + d, 1);
        edata[pos] = make_int2(ent.x, (int)h2u(__builtin_amdgcn_cvt_pkrtz(att, invd)));
    }
}

// ---- segment softmax + per-order gather-aggregate ----
// Fast path (deg <= 64, ~all nodes): single pass, one exp/edge.
__global__ void segagg(const int2* __restrict__ edata,
                       const int* __restrict__ rowptr,
                       const __fp16* __restrict__ fh,
                       __fp16* __restrict__ agg) {
    __shared__ uint4 stash[4][64];
    const int node = (blockIdx.x * blockDim.x + threadIdx.x) >> 6;
    const int lane = threadIdx.x & 63;
    const int wid  = threadIdx.x >> 6;
    if (node >= N_NODES) return;
    const int beg = rowptr[node], end = rowptr[node + 1];
    const int deg = end - beg;

    const int grp = lane >> 4;
    const int fl  = lane & 15;
    f16x2 ac[3][4];
    #pragma unroll
    for (int o = 0; o < 3; ++o)
        #pragma unroll
        for (int q = 0; q < 4; ++q) ac[o][q] = (f16x2){0, 0};

    auto STASH = [&](float wl, int so) {
        const int k = so >> 16;
        const __fp16 wh = (__fp16)wl;
        f16x2 w2; w2.x = wh; w2.y = wh;
        const unsigned uw = h2u(w2);
        stash[wid][lane] = make_uint4(k == 0 ? uw : 0u, k == 1 ? uw : 0u,
                                      k == 2 ? uw : 0u, (unsigned)(so & 0xFFFF));
    };
    auto GATHER = [&](int ne) {
        const uint4* st = stash[wid];
        for (int t = 0; t < ne; t += 8) {
            const uint4 e1 = st[t + grp];
            const uint4 e2 = st[t + 4 + grp];
            const uint4 v1 = *(const uint4*)(fh + ((size_t)e1.w << 7) + fl * 8);
            const uint4 v2 = *(const uint4*)(fh + ((size_t)e2.w << 7) + fl * 8);
            {
                const f16x2 w0 = u2h(e1.x), w1 = u2h(e1.y), w2v = u2h(e1.z);
                const f16x2 va = u2h(v1.x), vb = u2h(v1.y), vc = u2h(v1.z), vd = u2h(v1.w);
                ac[0][0] = __builtin_elementwise_fma(va, w0, ac[0][0]);
                ac[0][1] = __builtin_elementwise_fma(vb, w0, ac[0][1]);
                ac[0][2] = __builtin_elementwise_fma(vc, w0, ac[0][2]);
                ac[0][3] = __builtin_elementwise_fma(vd, w0, ac[0][3]);
                ac[1][0] = __builtin_elementwise_fma(va, w1, ac[1][0]);
                ac[1][1] = __builtin_elementwise_fma(vb, w1, ac[1][1]);
                ac[1][2] = __builtin_elementwise_fma(vc, w1, ac[1][2]);
                ac[1][3] = __builtin_elementwise_fma(vd, w1, ac[1][3]);
                ac[2][0] = __builtin_elementwise_fma(va, w2v, ac[2][0]);
                ac[2][1] = __builtin_elementwise_fma(vb, w2v, ac[2][1]);
                ac[2][2] = __builtin_elementwise_fma(vc, w2v, ac[2][2]);
                ac[2][3] = __builtin_elementwise_fma(vd, w2v, ac[2][3]);
            }
            {
                const f16x2 w0 = u2h(e2.x), w1 = u2h(e2.y), w2v = u2h(e2.z);
                const f16x2 va = u2h(v2.x), vb = u2h(v2.y), vc = u2h(v2.z), vd = u2h(v2.w);
                ac[0][0] = __builtin_elementwise_fma(va, w0, ac[0][0]);
                ac[0][1] = __builtin_elementwise_fma(vb, w0, ac[0][1]);
                ac[0][2] = __builtin_elementwise_fma(vc, w0, ac[0][2]);
                ac[0][3] = __builtin_elementwise_fma(vd, w0, ac[0][3]);
                ac[1][0] = __builtin_elementwise_fma(va, w1, ac[1][0]);
                ac[1][1] = __builtin_elementwise_fma(vb, w1, ac[1][1]);
                ac[1][2] = __builtin_elementwise_fma(vc, w1, ac[1][2]);
                ac[1][3] = __builtin_elementwise_fma(vd, w1, ac[1][3]);
                ac[2][0] = __builtin_elementwise_fma(va, w2v, ac[2][0]);
                ac[2][1] = __builtin_elementwise_fma(vb, w2v, ac[2][1]);
                ac[2][2] = __builtin_elementwise_fma(vc, w2v, ac[2][2]);
                ac[2][3] = __builtin_elementwise_fma(vd, w2v, ac[2][3]);
            }
        }
    };

    if (deg <= 64) {
        // single pass: load, max-reduce, exp, sum-reduce, gather
        int so = 0; float a = -1e30f, iv = 0.f;
        if (lane < deg) {
            const int2 e = edata[beg + lane];
            so = e.x;
            const f16x2 ai = u2h((unsigned)e.y);
            a  = (float)ai.x;
            iv = (float)ai.y;
        }
        float m = a;
        #pragma unroll
        for (int off = 32; off; off >>= 1) m = fmaxf(m, __shfl_xor(m, off));
        const float ex = (lane < deg) ? __expf(a - m) : 0.f;
        float s = ex;
        #pragma unroll
        for (int off = 32; off; off >>= 1) s += __shfl_xor(s, off);
        const float wl = ex * (s > 0.f ? 1.f / s : 0.f) * iv;
        STASH(wl, so);
        GATHER(deg);
    } else {
        // two-pass fallback (rare)
        float m = -1e30f, s = 0.f;
        for (int cb = beg; cb < end; cb += 64) {
            const int p = cb + lane;
            float a = -1e30f;
            if (p < end) a = (float)u2h((unsigned)edata[p].y).x;
            const float mn = fmaxf(m, a);
            s = s * __expf(m - mn) + ((p < end) ? __expf(a - mn) : 0.f);
            m = mn;
        }
        #pragma unroll
        for (int off = 32; off; off >>= 1) {
            const float mo = __shfl_xor(m, off), so_ = __shfl_xor(s, off);
            const float mn = fmaxf(m, mo);
            s = s * __expf(m - mn) + so_ * __expf(mo - mn);
            m = mn;
        }
        const float inv_s = s > 0.f ? 1.f / s : 0.f;
        for (int cb = beg; cb < end; cb += 64) {
            const int p = cb + lane;
            float wl = 0.f; int so = 0;
            if (p < end) {
                const int2 e = edata[p];
                so = e.x;
                const f16x2 ai = u2h((unsigned)e.y);
                wl = __expf((float)ai.x - m) * inv_s * (float)ai.y;
            }
            STASH(wl, so);
            GATHER(min(64, end - cb));
        }
    }

    #pragma unroll
    for (int o = 0; o < 3; ++o)
        #pragma unroll
        for (int q = 0; q < 4; ++q) {
            ac[o][q] = ac[o][q] + u2h(__shfl_xor((int)h2u(ac[o][q]), 16));
            ac[o][q] = ac[o][q] + u2h(__shfl_xor((int)h2u(ac[o][q]), 32));
        }
    if (lane < 16) {
        __fp16* row = agg + (size_t)node * 384 + fl * 8;
        *(uint4*)(row)       = make_uint4(h2u(ac[0][0]), h2u(ac[0][1]), h2u(ac[0][2]), h2u(ac[0][3]));
        *(uint4*)(row + 128) = make_uint4(h2u(ac[1][0]), h2u(ac[1][1]), h2u(ac[1][2]), h2u(ac[1][3]));
        *(uint4*)(row + 256) = make_uint4(h2u(ac[2][0]), h2u(ac[2][1]), h2u(ac[2][2]), h2u(ac[2][3]));
    }
}

// ============================================================================
// mlp_gemm: yh[m,o] = f16(relu(sum_{ki<384} agg[m,ki]*GT[o,ki] + b[o])) + stats
// ============================================================================
__global__ __launch_bounds__(256)
void mlp_gemm(const __fp16* __restrict__ agg, const __fp16* __restrict__ GT,
              __fp16* __restrict__ yh, int M,
              const float* __restrict__ bias, float* __restrict__ sbuf) {
    __shared__ char smem[49152];
    const int m0 = blockIdx.x * 64;
    const int tid = threadIdx.x;
    const int wave = tid >> 6, lane = tid & 63;
    const int wm0 = wave * 16;
    const int lrow = lane & 15;
    const int kg = lane >> 4;
    const int srow = lane >> 3;
    const int schunk = lane & 7;

    auto STAGE = [&](int buf, int kc) {
        char* base = smem + buf * 24576;
        #pragma unroll
        for (int j = 0; j < 2; ++j) {
            const int rl = wave * 16 + j * 8 + srow;
            const int rg = min(m0 + rl, M - 1);
            gload16(agg + (size_t)rg * 384 + kc * 64 + ((schunk ^ (rl & 7)) << 3),
                    base + (wave * 16 + j * 8) * 128);
        }
        #pragma unroll
        for (int j = 0; j < 4; ++j) {
            const int rl = wave * 32 + j * 8 + srow;
            gload16(GT + (size_t)rl * 384 + kc * 64 + ((schunk ^ (rl & 7)) << 3),
                    base + 8192 + (wave * 32 + j * 8) * 128);
        }
    };

    f32x4 acc[8];
    #pragma unroll
    for (int b = 0; b < 8; ++b) acc[b] = (f32x4){0.f, 0.f, 0.f, 0.f};

    STAGE(0, 0);
    __syncthreads();

    for (int kc = 0; kc < 6; ++kc) {
        const int buf = kc & 1;
        if (kc < 5) STAGE(buf ^ 1, kc + 1);
        const char* Ab = smem + buf * 24576;
        const char* Bb = Ab + 8192;
        f16x8 afr[2];
        #pragma unroll
        for (int ks = 0; ks < 2; ++ks) {
            const int row = wm0 + lrow;
            afr[ks] = *(const f16x8*)(Ab + row * 128 + (((ks * 4 + kg) ^ (row & 7)) << 4));
        }
        #pragma unroll
        for (int nf = 0; nf < 8; ++nf) {
            #pragma unroll
            for (int ks = 0; ks < 2; ++ks) {
                const int row = nf * 16 + lrow;
                f16x8 bfr = *(const f16x8*)(Bb + row * 128 + (((ks * 4 + kg) ^ (row & 7)) << 4));
                acc[nf] = __builtin_amdgcn_mfma_f32_16x16x32_f16(afr[ks], bfr, acc[nf], 0, 0, 0);
            }
        }
        __syncthreads();
    }

    float s[8], s2[8], bv[8];
    #pragma unroll
    for (int nf = 0; nf < 8; ++nf) { s[nf] = 0.f; s2[nf] = 0.f; bv[nf] = bias[nf * 16 + lrow]; }
    #pragma unroll
    for (int nf = 0; nf < 8; ++nf)
        #pragma unroll
        for (int rg = 0; rg < 4; ++rg) {
            const int row = m0 + wm0 + kg * 4 + rg;
            if (row < M) {
                const float v = fmaxf(acc[nf][rg] + bv[nf], 0.f);
                yh[(size_t)row * FEAT + nf * 16 + lrow] = (__fp16)v;
                s[nf] += v;
                s2[nf] = fmaf(v, v, s2[nf]);
            }
        }
    #pragma unroll
    for (int nf = 0; nf < 8; ++nf) {
        s[nf]  += __shfl_xor(s[nf], 16);  s[nf]  += __shfl_xor(s[nf], 32);
        s2[nf] += __shfl_xor(s2[nf], 16); s2[nf] += __shfl_xor(s2[nf], 32);
    }
    __syncthreads();
    float* red = (float*)smem;
    if (lane < 16) {
        #pragma unroll
        for (int nf = 0; nf < 8; ++nf) {
            red[wave * 256 + nf * 16 + lane]       = s[nf];
            red[wave * 256 + 128 + nf * 16 + lane] = s2[nf];
        }
    }
    __syncthreads();
    if (tid < 128) {
        const float ss = red[tid] + red[256 + tid] + red[512 + tid] + red[768 + tid];
        const float qq = red[128 + tid] + red[384 + tid] + red[640 + tid] + red[896 + tid];
        float* sb = sbuf + (blockIdx.x & (NSHARD - 1)) * 256;
        atomicAdd(sb + tid, ss);
        atomicAdd(sb + FEAT + tid, qq);
    }
}

// ---- BN normalize: read yh (f16), write out (f32) ----
__global__ void normalize(const __fp16* __restrict__ yh, float* __restrict__ out,
                          const float* __restrict__ sbuf,
                          const float* __restrict__ gamma, const float* __restrict__ beta) {
    __shared__ float sc_s[FEAT], sh_s[FEAT];
    const int t = threadIdx.x;
    if (t < FEAT) {
        float ssum = 0.f, qsum = 0.f;
        #pragma unroll
        for (int sh = 0; sh < NSHARD; ++sh) {
            ssum += sbuf[sh * 256 + t];
            qsum += sbuf[sh * 256 + 128 + t];
        }
        const float mean = ssum / (float)N_NODES;
        const float var  = qsum / (float)N_NODES - mean * mean;
        const float sc   = gamma[t] * rsqrtf(var + BN_EPS);
        sc_s[t] = sc;
        sh_s[t] = beta[t] - mean * sc;
    }
    __syncthreads();
    const int idx = blockIdx.x * 256 + t;    // 800,000 total (exact)
    const int f0 = (idx & 15) * 8;
    const uint4 hv = *(const uint4*)(yh + (size_t)idx * 8);
    const f16x2 h0 = u2h(hv.x), h1 = u2h(hv.y), h2v = u2h(hv.z), h3 = u2h(hv.w);
    float4 o0, o1;
    o0.x = fmaf((float)h0.x,  sc_s[f0 + 0], sh_s[f0 + 0]);
    o0.y = fmaf((float)h0.y,  sc_s[f0 + 1], sh_s[f0 + 1]);
    o0.z = fmaf((float)h1.x,  sc_s[f0 + 2], sh_s[f0 + 2]);
    o0.w = fmaf((float)h1.y,  sc_s[f0 + 3], sh_s[f0 + 3]);
    o1.x = fmaf((float)h2v.x, sc_s[f0 + 4], sh_s[f0 + 4]);
    o1.y = fmaf((float)h2v.y, sc_s[f0 + 5], sh_s[f0 + 5]);
    o1.z = fmaf((float)h3.x,  sc_s[f0 + 6], sh_s[f0 + 6]);
    o1.w = fmaf((float)h3.y,  sc_s[f0 + 7], sh_s[f0 + 7]);
    *(float4*)(out + (size_t)idx * 8)     = o0;
    *(float4*)(out + (size_t)idx * 8 + 4) = o1;
}

extern "C" void kernel_launch(void* const* d_in, const int* in_sizes, int n_in,
                              void* d_out, int out_size, void* d_ws, size_t ws_size,
                              hipStream_t stream) {
    const float* feature = (const float*)d_in[0];
    const float* coords  = (const float*)d_in[1];
    const int*   src     = (const int*)d_in[2];
    const int*   dst     = (const int*)d_in[3];
    const int*   order   = (const int*)d_in[4];
    const float* linear  = (const float*)d_in[5];
    const float* attW    = (const float*)d_in[6];
    const float* mlp_w   = (const float*)d_in[7];
    const float* mlp_b   = (const float*)d_in[8];
    const float* gamma   = (const float*)d_in[9];
    const float* beta    = (const float*)d_in[10];
    float* out = (float*)d_out;

    char* p = (char*)d_ws;
    __fp16* fh           = (__fp16*)p;  p += (size_t)N_NODES * FEAT * 2;   // 12.8 MB (reused as yh)
    __fp16* agg          = (__fp16*)p;  p += (size_t)N_NODES * 384 * 2;    // 38.4 MB
    __fp16* GT           = (__fp16*)p;  p += (size_t)FEAT * 384 * 2;       // 98 KB
    float4* pk           = (float4*)p;  p += (size_t)N_NODES * 32;         // 1.6 MB
    int2*  edata         = (int2*)p;    p += (size_t)E_EDGES * 8;          // 6.4 MB
    int2*  bbuf          = (int2*)p;    p += (size_t)NBUK * BCAP * 8;      // 8.0 MB
    float* sbuf          = (float*)p;   p += NSHARD * 256 * 4;             // 4096 floats
    int*   gcur          = (int*)p;     p += 1024;                         // 256 ints
    int*   rowptr        = (int*)p;     p += 200064;
    int*   cursor        = (int*)p;     p += 200064;

    const int MB = (N_NODES + 63) / 64;          // 782
    const int AB = (E_EDGES + 2047) / 2048;      // 391

    // zeroing of sbuf|gcur happens inside g_cast (NZERO ints from sbuf)
    g_cast<<<NGC_BLKS + FEAT, 256, 0, stream>>>(feature, coords, attW,
                                                mlp_w, linear, fh, pk, GT, (int*)sbuf);

    bucketA<<<AB, 256, 0, stream>>>(src, dst, order, gcur, bbuf);
    hist2<<<NBUK, 256, 0, stream>>>(gcur, bbuf, rowptr, cursor);
    bucketB<<<NBUK * NSEG, 256, 0, stream>>>(gcur, bbuf, pk, cursor, edata);

    segagg<<<NWB_BLKS, 256, 0, stream>>>(edata, rowptr, fh, agg);

    mlp_gemm<<<MB, 256, 0, stream>>>(agg, GT, fh /*as yh*/, N_NODES, mlp_b, sbuf);
    normalize<<<(N_NODES * FEAT / 8 + 255) / 256, 256, 0, stream>>>(fh, out, sbuf, gamma, beta);
}